// Round 12
// baseline (186.556 us; speedup 1.0000x reference)
//
#include <hip/hip_runtime.h>
#include <math.h>

#define BB 16
#define CC 256
#define C3 768
#define HH 56
#define WW 56
#define HWSZ 3136
#define HEADS 8
#define HD 32
#define EPSF 1e-12f
#define NCHUNK 7
#define SLAB 1088             // 32*32 gram + 32 q-sumsq + 32 k-sumsq

using s16x8 = __attribute__((ext_vector_type(8))) short;
using u16x8 = __attribute__((ext_vector_type(8))) unsigned short;
using u16x4 = __attribute__((ext_vector_type(4))) unsigned short;
using f32x4 = __attribute__((ext_vector_type(4))) float;
using f32x16 = __attribute__((ext_vector_type(16))) float;

__device__ inline unsigned short f2bf(float f) {
    unsigned int u = __float_as_uint(f);
    return (unsigned short)((u + 0x7FFFu + ((u >> 16) & 1u)) >> 16);
}
__device__ inline float bf2f(unsigned short s) {
    return __uint_as_float((unsigned int)s << 16);
}
__device__ inline void gload16(const unsigned short* g, const unsigned short* l) {
    __builtin_amdgcn_global_load_lds(
        (const __attribute__((address_space(1))) void*)g,
        (__attribute__((address_space(3))) void*)l, 16, 0, 0);
}

// ---------------------------------------------------------------------------
// Convert + transpose: x fp32 [256][3136] -> xbT bf16 [3136][256] (per batch).
// grid (49, 4, BB), block 256.
// ---------------------------------------------------------------------------
__global__ __launch_bounds__(256)
void cvt_x_T(const float* __restrict__ X, unsigned short* __restrict__ XT)
{
    __shared__ float L[64][65];
    const int t = threadIdx.x;
    const int n0 = blockIdx.x * 64;
    const int c0 = blockIdx.y * 64;
    const long bofX = (long)blockIdx.z * CC * HWSZ;
    const long bofT = (long)blockIdx.z * HWSZ * CC;
#pragma unroll
    for (int l = 0; l < 4; ++l) {
        int idx = l * 256 + t;
        int ch = idx >> 4, n4 = (idx & 15) * 4;
        float4 v = *(const float4*)&X[bofX + (long)(c0 + ch) * HWSZ + n0 + n4];
        L[n4 + 0][ch] = v.x; L[n4 + 1][ch] = v.y;
        L[n4 + 2][ch] = v.z; L[n4 + 3][ch] = v.w;
    }
    __syncthreads();
#pragma unroll
    for (int l = 0; l < 2; ++l) {
        int idx = l * 256 + t;
        int r = idx >> 3, c8 = (idx & 7) * 8;
        u16x8 o;
#pragma unroll
        for (int e = 0; e < 8; ++e) o[e] = f2bf(L[r][c8 + e]);
        *(u16x8*)&XT[bofT + (long)(n0 + r) * CC + c0 + c8] = o;
    }
}

// ---------------------------------------------------------------------------
// Transpose v: dw16 v-section [b][k=256][3136] bf16 -> vT [b*3136+n][256].
// Same structure as cvt_x_T (bf16->f32->bf16 roundtrip is exact).
// grid (49, 4, BB), block 256.
// ---------------------------------------------------------------------------
__global__ __launch_bounds__(256)
void cvt_v_T(const unsigned short* __restrict__ dw, unsigned short* __restrict__ VT)
{
    __shared__ float L[64][65];
    const int t = threadIdx.x;
    const int n0 = blockIdx.x * 64;
    const int c0 = blockIdx.y * 64;
    const long bofV = ((long)blockIdx.z * C3 + 2 * CC) * HWSZ;
    const long bofT = (long)blockIdx.z * HWSZ * CC;
#pragma unroll
    for (int l = 0; l < 4; ++l) {
        int idx = l * 256 + t;
        int ch = idx >> 4, n4 = (idx & 15) * 4;
        u16x4 v = *(const u16x4*)&dw[bofV + (long)(c0 + ch) * HWSZ + n0 + n4];
        L[n4 + 0][ch] = bf2f(v[0]); L[n4 + 1][ch] = bf2f(v[1]);
        L[n4 + 2][ch] = bf2f(v[2]); L[n4 + 3][ch] = bf2f(v[3]);
    }
    __syncthreads();
#pragma unroll
    for (int l = 0; l < 2; ++l) {
        int idx = l * 256 + t;
        int r = idx >> 3, c8 = (idx & 7) * 8;
        u16x8 o;
#pragma unroll
        for (int e = 0; e < 8; ++e) o[e] = f2bf(L[r][c8 + e]);
        *(u16x8*)&VT[bofT + (long)(n0 + r) * CC + c0 + c8] = o;
    }
}

// ---------------------------------------------------------------------------
// fp32 -> bf16 flat convert (qkv weights). n multiple of 2048; grid n/2048.
// ---------------------------------------------------------------------------
__global__ __launch_bounds__(256)
void cvt_w(const float* __restrict__ A, unsigned short* __restrict__ B)
{
    int i = (blockIdx.x * 256 + threadIdx.x) * 8;
    float4 a = *(const float4*)&A[i];
    float4 b = *(const float4*)&A[i + 4];
    u16x8 o;
    o[0] = f2bf(a.x); o[1] = f2bf(a.y); o[2] = f2bf(a.z); o[3] = f2bf(a.w);
    o[4] = f2bf(b.x); o[5] = f2bf(b.y); o[6] = f2bf(b.z); o[7] = f2bf(b.w);
    *(u16x8*)&B[i] = o;
}

// ---------------------------------------------------------------------------
// m97-style GEMM, gload16 BOTH operands (measured-best structure, R5):
//   Y[m][n] = sum_k A[m][k] * B[n][k], K=256, 128x128 tile, BK=64, dbuf 64KB.
// Swapped-operand MFMA epilogue: lane holds 4 consecutive n at fixed m ->
// vectorized C-stores (u16x4 / float4).
// MODE 0 (qkv): A=wqb [768][256], B=xbT [50176][256], Y=tmp bf16 [768][50176];
//               MT=6, grid 2352, no tails.
// MODE 1 (proj): z=blockIdx.y; A=Mm[z] [256][256], B=vT+z*HWSZ*256 (padded),
//               Y=out fp32 [z][256][3136]; MT=2, grid (50, 16), tail guarded.
// ---------------------------------------------------------------------------
template<int MODE>
__global__ __launch_bounds__(256)
void gemm_g(const unsigned short* __restrict__ Ab,
            const unsigned short* __restrict__ Bb,
            void* __restrict__ Yv)
{
    constexpr int MT = (MODE == 0) ? 6 : 2;
    __shared__ __align__(16) unsigned short S[32768];   // 2 x (A 16KB + B 16KB)
    const int t = threadIdx.x;
    const int w = t >> 6, lane = t & 63;

    const int nwg = (int)gridDim.x;
    const int bid = (int)blockIdx.x;
    const int q8 = nwg >> 3, r8 = nwg & 7;
    const int xcd = bid & 7, idx = bid >> 3;
    const int sw = (xcd < r8 ? xcd * (q8 + 1) : r8 * (q8 + 1) + (xcd - r8) * q8) + idx;
    const int mt = sw % MT, nt = sw / MT;
    const int m0 = mt * 128;
    const int n0 = nt * 128;
    const int z = (MODE == 1) ? (int)blockIdx.y : 0;

    const int rl  = lane >> 3;
    const int gsw = ((lane & 7) ^ rl) << 3;
    const int lr = lane & 15, gq = lane >> 4;
    const int m_off = (w >> 1) * 64, n_off = (w & 1) * 64;

    const unsigned short* GA = Ab + ((MODE == 1) ? (long)z * CC * CC : 0)
                                  + (long)m0 * 256;
    const unsigned short* GB = Bb + ((MODE == 1) ? (long)z * HWSZ * CC : 0)
                                  + (long)n0 * 256;

    f32x4 acc[4][4];
#pragma unroll
    for (int i = 0; i < 4; ++i)
#pragma unroll
        for (int j = 0; j < 4; ++j) acc[i][j] = (f32x4){0.f, 0.f, 0.f, 0.f};

#define STAGE(buf, kt)                                                        \
    {                                                                         \
        const unsigned short* L = S + (buf) * 16384;                          \
        const unsigned short* ga = GA + (kt) * 64;                            \
        const unsigned short* gb = GB + (kt) * 64;                            \
        _Pragma("unroll")                                                     \
        for (int qq = 0; qq < 4; ++qq) {                                      \
            int R = w * 32 + qq * 8;                                          \
            gload16(ga + (long)(R + rl) * 256 + gsw, L + R * 64);             \
            gload16(gb + (long)(R + rl) * 256 + gsw, L + 8192 + R * 64);      \
        }                                                                     \
    }

    STAGE(0, 0);
    __syncthreads();
#pragma unroll
    for (int kt = 0; kt < 4; ++kt) {
        if (kt < 3) STAGE((kt + 1) & 1, kt + 1);
        const unsigned short* L = S + (kt & 1) * 16384;
        s16x8 af[4][2], bf[4][2];
#pragma unroll
        for (int i = 0; i < 4; ++i) {
            int r = m_off + i * 16 + lr;
#pragma unroll
            for (int ks = 0; ks < 2; ++ks)
                af[i][ks] = *(const s16x8*)&L[r * 64 + (((gq + ks * 4) ^ (r & 7)) << 3)];
        }
#pragma unroll
        for (int j = 0; j < 4; ++j) {
            int r = n_off + j * 16 + lr;
#pragma unroll
            for (int ks = 0; ks < 2; ++ks)
                bf[j][ks] = *(const s16x8*)&L[8192 + r * 64 + (((gq + ks * 4) ^ (r & 7)) << 3)];
        }
        // swapped operands: lane -> fixed m (lane&15), n quad ((lane>>4)*4)
#pragma unroll
        for (int ks = 0; ks < 2; ++ks)
#pragma unroll
            for (int i = 0; i < 4; ++i)
#pragma unroll
                for (int j = 0; j < 4; ++j)
                    acc[i][j] = __builtin_amdgcn_mfma_f32_16x16x32_bf16(
                        bf[j][ks], af[i][ks], acc[i][j], 0, 0, 0);
        __syncthreads();
    }
#undef STAGE

    const int om = lane & 15, on = (lane >> 4) * 4;
    if (MODE == 0) {
        unsigned short* Yb = (unsigned short*)Yv;
        const long Nn = (long)BB * HWSZ;
#pragma unroll
        for (int i = 0; i < 4; ++i) {
            long row = m0 + m_off + i * 16 + om;
#pragma unroll
            for (int j = 0; j < 4; ++j) {
                long col = n0 + n_off + j * 16 + on;
                u16x4 v;
#pragma unroll
                for (int r = 0; r < 4; ++r) v[r] = f2bf(acc[i][j][r]);
                *(u16x4*)&Yb[row * Nn + col] = v;
            }
        }
    } else {
        float* Yb = (float*)Yv + (long)z * CC * HWSZ;
#pragma unroll
        for (int i = 0; i < 4; ++i) {
            int row = m0 + m_off + i * 16 + om;
#pragma unroll
            for (int j = 0; j < 4; ++j) {
                int col = n0 + n_off + j * 16 + on;
                if (col < HWSZ)
                    *(float4*)&Yb[(long)row * HWSZ + col] =
                        make_float4(acc[i][j][0], acc[i][j][1],
                                    acc[i][j][2], acc[i][j][3]);
            }
        }
    }
}

// ---------------------------------------------------------------------------
// Depthwise 3x3, pad 1 — LDS plane kernel, 4 px/thread via float4 row reads.
// ---------------------------------------------------------------------------
__global__ __launch_bounds__(256)
void dwconv3x3(const unsigned short* __restrict__ X,
               const float* __restrict__ Wd,
               unsigned short* __restrict__ Y,
               long Nn)
{
    __shared__ float P[HWSZ];
    const int ch = blockIdx.x;
    const int z = blockIdx.y;
    const int t = threadIdx.x;
    const unsigned short* xc = X + (long)ch * Nn + (long)z * HWSZ;
#pragma unroll
    for (int l = 0; l < 3; ++l) {
        int q4 = l * 256 + t;
        u16x4 v = *(const u16x4*)&xc[q4 * 4];
        *(float4*)&P[q4 * 4] =
            make_float4(bf2f(v[0]), bf2f(v[1]), bf2f(v[2]), bf2f(v[3]));
    }
    if (t < 16) {
        int q4 = 768 + t;
        u16x4 v = *(const u16x4*)&xc[q4 * 4];
        *(float4*)&P[q4 * 4] =
            make_float4(bf2f(v[0]), bf2f(v[1]), bf2f(v[2]), bf2f(v[3]));
    }
    float w9[9];
#pragma unroll
    for (int q = 0; q < 9; ++q) w9[q] = Wd[ch * 9 + q];
    __syncthreads();

    unsigned short* yc = Y + ((long)z * C3 + ch) * HWSZ;
    const int lane = t & 63;
#pragma unroll
    for (int l = 0; l < 4; ++l) {
        int g4 = l * 256 + t;
        if (g4 < 784) {
            int qi = g4 / 14, qj = g4 - qi * 14;
            float o0 = 0.f, o1 = 0.f, o2 = 0.f, o3 = 0.f;
#pragma unroll
            for (int di = 0; di < 3; ++di) {
                int ii = qi + di - 1;
                if ((unsigned)ii >= HH) continue;
                const float* Pr = &P[ii * WW + qj * 4];
                float4 v = *(const float4*)Pr;
                float lf = __shfl_up(v.w, 1);
                float rt = __shfl_down(v.x, 1);
                if (lane == 0 && qj != 0)   lf = Pr[-1];
                if (lane == 63 && qj != 13) rt = Pr[4];
                if (qj == 0)  lf = 0.f;
                if (qj == 13) rt = 0.f;
                const float wL = w9[di * 3 + 0], wC = w9[di * 3 + 1], wR = w9[di * 3 + 2];
                o0 += wL * lf  + wC * v.x + wR * v.y;
                o1 += wL * v.x + wC * v.y + wR * v.z;
                o2 += wL * v.y + wC * v.z + wR * v.w;
                o3 += wL * v.z + wC * v.w + wR * rt;
            }
            u16x4 ov;
            ov[0] = f2bf(o0); ov[1] = f2bf(o1); ov[2] = f2bf(o2); ov[3] = f2bf(o3);
            *(u16x4*)&yc[g4 * 4] = ov;
        }
    }
}

// ---------------------------------------------------------------------------
// Gram via MFMA: partial Q.K^T + diag norms per (chunk, h, b). grid (7,8,16).
// ---------------------------------------------------------------------------
__global__ __launch_bounds__(256)
void gram_mfma(const unsigned short* __restrict__ dw, float* __restrict__ gram)
{
    __shared__ float Sred[SLAB];
    const int c = blockIdx.x, h = blockIdx.y, b = blockIdx.z;
    const int t = threadIdx.x;
    const int w = t >> 6, lane = t & 63;
    const unsigned short* qb = dw + ((long)b * C3 + h * HD) * HWSZ;
    const unsigned short* kb = dw + ((long)b * C3 + CC + h * HD) * HWSZ;

    for (int l = t; l < SLAB; l += 256) Sred[l] = 0.f;

    const int row = lane & 31;
    const int hi  = lane >> 5;
    const long rbase = (long)row * HWSZ + hi * 8;

    f32x16 aqk, aqq, akk;
#pragma unroll
    for (int i = 0; i < 16; ++i) { aqk[i] = 0.f; aqq[i] = 0.f; akk[i] = 0.f; }

#pragma unroll
    for (int s = 0; s < 7; ++s) {
        int p0 = (c * 28 + w * 7 + s) * 16;
        s16x8 qf = *(const s16x8*)&qb[rbase + p0];
        s16x8 kf = *(const s16x8*)&kb[rbase + p0];
        aqk = __builtin_amdgcn_mfma_f32_32x32x16_bf16(qf, kf, aqk, 0, 0, 0);
        aqq = __builtin_amdgcn_mfma_f32_32x32x16_bf16(qf, qf, aqq, 0, 0, 0);
        akk = __builtin_amdgcn_mfma_f32_32x32x16_bf16(kf, kf, akk, 0, 0, 0);
    }
    __syncthreads();

#pragma unroll
    for (int r = 0; r < 16; ++r) {
        int rowd = (r & 3) + 8 * (r >> 2) + 4 * hi;
        atomicAdd(&Sred[rowd * 32 + row], aqk[r]);
    }
    {
        int dreg = (row & 3) | ((row >> 3) << 2);
        bool has = ((row >> 2) & 1) == hi;
        float qd = has ? aqq[dreg] : 0.f;
        float kd = has ? akk[dreg] : 0.f;
        qd += __shfl_xor(qd, 32);
        kd += __shfl_xor(kd, 32);
        if (hi == 0) {
            atomicAdd(&Sred[1024 + row], qd);
            atomicAdd(&Sred[1056 + row], kd);
        }
    }
    __syncthreads();
    float* slab = gram + (((long)c * BB + b) * HEADS + h) * SLAB;
    for (int l = t; l < SLAB; l += 256) slab[l] = Sred[l];
}

// ---------------------------------------------------------------------------
// Sum slabs, normalize, temperature, softmax over j; write TRANSPOSED
// attn: atT[b][h][j][i] (fp32) for the mprep MFMA B-operand. grid (8,16).
// ---------------------------------------------------------------------------
__global__ __launch_bounds__(1024)
void attn_finish(const float* __restrict__ gram,
                 const float* __restrict__ temp,
                 float* __restrict__ attnT)
{
    __shared__ float nrm[64];
    const int h = blockIdx.x, b = blockIdx.y;
    const int t = threadIdx.x;
    const long sbase = ((long)b * HEADS + h) * SLAB;
    const long cstr  = (long)BB * HEADS * SLAB;
    if (t < 64) {
        float s = 0.f;
#pragma unroll
        for (int c = 0; c < NCHUNK; ++c) s += gram[c * cstr + sbase + 1024 + t];
        nrm[t] = fmaxf(sqrtf(s), EPSF);
    }
    __syncthreads();
    const int i = t >> 5, j = t & 31;
    float s = 0.f;
#pragma unroll
    for (int c = 0; c < NCHUNK; ++c) s += gram[c * cstr + sbase + i * 32 + j];
    s *= temp[h] / (nrm[i] * nrm[32 + j]);
    float mx = s;
    mx = fmaxf(mx, __shfl_xor(mx, 1));
    mx = fmaxf(mx, __shfl_xor(mx, 2));
    mx = fmaxf(mx, __shfl_xor(mx, 4));
    mx = fmaxf(mx, __shfl_xor(mx, 8));
    mx = fmaxf(mx, __shfl_xor(mx, 16));
    float e = expf(s - mx);
    float sum = e;
    sum += __shfl_xor(sum, 1); sum += __shfl_xor(sum, 2);
    sum += __shfl_xor(sum, 4); sum += __shfl_xor(sum, 8);
    sum += __shfl_xor(sum, 16);
    attnT[(((long)b * HEADS + h) * HD + j) * HD + i] = e / sum;
}

// ---------------------------------------------------------------------------
// M[b] = Wp x blockdiag(attn). grid (16), block 256. Output bf16 [256][256].
// ---------------------------------------------------------------------------
__global__ __launch_bounds__(256)
void mprep(const float* __restrict__ Wp,
           const float* __restrict__ atT,
           unsigned short* __restrict__ Mm)
{
    const int zb = blockIdx.x;
    const int t = threadIdx.x, w = t >> 6, lane = t & 63;
    const int lr = lane & 15, gq = lane >> 4;
    const int m_base = w * 64;
    const float* atb = atT + (long)zb * HEADS * HD * HD;
    unsigned short* Mb = Mm + (long)zb * CC * CC;

#pragma unroll
    for (int h = 0; h < 8; ++h) {
        s16x8 bf[2];
#pragma unroll
        for (int jt = 0; jt < 2; ++jt) {
            const float* src = atb + (long)(h * 32 + jt * 16 + lr) * 32 + gq * 8;
            float4 a = *(const float4*)src;
            float4 b = *(const float4*)(src + 4);
            s16x8 v;
            v[0] = (short)f2bf(a.x); v[1] = (short)f2bf(a.y);
            v[2] = (short)f2bf(a.z); v[3] = (short)f2bf(a.w);
            v[4] = (short)f2bf(b.x); v[5] = (short)f2bf(b.y);
            v[6] = (short)f2bf(b.z); v[7] = (short)f2bf(b.w);
            bf[jt] = v;
        }
#pragma unroll
        for (int i = 0; i < 4; ++i) {
            const float* src = Wp + (long)(m_base + i * 16 + lr) * 256 + h * 32 + gq * 8;
            float4 a = *(const float4*)src;
            float4 b = *(const float4*)(src + 4);
            s16x8 af;
            af[0] = (short)f2bf(a.x); af[1] = (short)f2bf(a.y);
            af[2] = (short)f2bf(a.z); af[3] = (short)f2bf(a.w);
            af[4] = (short)f2bf(b.x); af[5] = (short)f2bf(b.y);
            af[6] = (short)f2bf(b.z); af[7] = (short)f2bf(b.w);
#pragma unroll
            for (int jt = 0; jt < 2; ++jt) {
                f32x4 acc = (f32x4){0.f, 0.f, 0.f, 0.f};
                acc = __builtin_amdgcn_mfma_f32_16x16x32_bf16(af, bf[jt], acc, 0, 0, 0);
#pragma unroll
                for (int r = 0; r < 4; ++r)
                    Mb[(long)(m_base + i * 16 + gq * 4 + r) * 256
                       + h * 32 + jt * 16 + lr] = f2bf(acc[r]);
            }
        }
    }
}

// ---------------------------------------------------------------------------
extern "C" void kernel_launch(void* const* d_in, const int* in_sizes, int n_in,
                              void* d_out, int out_size, void* d_ws, size_t ws_size,
                              hipStream_t stream)
{
    const float* x      = (const float*)d_in[0];
    const float* w_qkv  = (const float*)d_in[1];
    const float* w_dw   = (const float*)d_in[2];
    const float* w_proj = (const float*)d_in[3];
    const float* temp   = (const float*)d_in[4];
    float* out = (float*)d_out;
    float* ws  = (float*)d_ws;

    const size_t atF = (size_t)BB * HEADS * HD * HD;           // 131,072 f
    const size_t grF = (size_t)NCHUNK * BB * HEADS * SLAB;     // 974,848 f
    const size_t dwE = (size_t)BB * C3 * HWSZ;                 // u16
    const size_t wqE = (size_t)C3 * CC;                        // u16
    const size_t mmE = (size_t)BB * CC * CC;                   // u16
    const size_t xbE = (size_t)BB * HWSZ * CC;                 // u16
    const size_t vtE = xbE + 64 * CC;                          // u16 (+64-row pad)

    float* atT  = ws;
    float* gram = ws + atF;
    unsigned short* dw16 = (unsigned short*)(ws + atF + grF);
    unsigned short* wqb  = dw16 + dwE;
    unsigned short* Mm   = wqb + wqE;
    unsigned short* xbT  = Mm + mmE;
    unsigned short* vT   = xbT + xbE;
    unsigned short* tmp  = vT + vtE;
    // ~213 MB total, fits the >=268 MB workspace

    cvt_w<<<dim3((C3 * CC) / 2048), 256, 0, stream>>>(w_qkv, wqb);
    cvt_x_T<<<dim3(49, 4, BB), 256, 0, stream>>>(x, xbT);

    // qkv: [768 x 50176 x 256], A & B via gload16. 6*392 = 2352 wgs.
    gemm_g<0><<<dim3(2352), 256, 0, stream>>>(wqb, xbT, tmp);

    dwconv3x3<<<dim3(C3, BB), 256, 0, stream>>>(tmp, w_dw, dw16, (long)BB * HWSZ);

    gram_mfma<<<dim3(NCHUNK, HEADS, BB), 256, 0, stream>>>(dw16, gram);
    attn_finish<<<dim3(HEADS, BB), 1024, 0, stream>>>(gram, temp, atT);
    mprep<<<dim3(BB), 256, 0, stream>>>(w_proj, atT, Mm);
    cvt_v_T<<<dim3(49, 4, BB), 256, 0, stream>>>(dw16, vT);

    // proj: per-z [256 x 3136 x 256], A = M[z], B = vT. grid (50, 16).
    gemm_g<1><<<dim3(50, BB), 256, 0, stream>>>(Mm, vT, out);
}